// Round 1
// baseline (393.152 us; speedup 1.0000x reference)
//
#include <hip/hip_runtime.h>
#include <math.h>

#define NN 50000
#define NE 800000
#define DD 64

// -------------------- kernels --------------------

__global__ void k_gather(const float* __restrict__ emb, const int* __restrict__ ids,
                         float* __restrict__ h0) {
  int idx = blockIdx.x * 256 + threadIdx.x;
  if (idx >= NN * DD) return;
  int node = idx >> 6, d = idx & 63;
  h0[idx] = emb[ids[node] * DD + d];
}

__global__ void k_hist(const int* __restrict__ dst, int* __restrict__ deg) {
  int e = blockIdx.x * 256 + threadIdx.x;
  if (e < NE) atomicAdd(&deg[dst[e]], 1);
}

__global__ void k_scan1(const int* __restrict__ deg, int* __restrict__ rp,
                        int* __restrict__ bsum) {
  __shared__ int tmp[1024];
  int t = threadIdx.x;
  int i = blockIdx.x * 1024 + t;
  int v = (i < NN) ? deg[i] : 0;
  tmp[t] = v;
  __syncthreads();
  for (int off = 1; off < 1024; off <<= 1) {
    int x = (t >= off) ? tmp[t - off] : 0;
    __syncthreads();
    tmp[t] += x;
    __syncthreads();
  }
  if (i < NN) rp[i] = tmp[t] - v;  // exclusive within block
  if (t == 1023) bsum[blockIdx.x] = tmp[1023];
}

__global__ void k_scan2(int* __restrict__ bsum, int nb) {
  if (threadIdx.x == 0 && blockIdx.x == 0) {
    int r = 0;
    for (int i = 0; i < nb; ++i) { int v = bsum[i]; bsum[i] = r; r += v; }
  }
}

__global__ void k_scan3(int* __restrict__ rp, const int* __restrict__ bsum) {
  int i = blockIdx.x * 1024 + threadIdx.x;
  if (i < NN) rp[i] += bsum[blockIdx.x];
  if (i == 0) rp[NN] = NE;
}

__global__ void k_scatter(const int* __restrict__ src, const int* __restrict__ dst,
                          const int* __restrict__ rp, int* __restrict__ fill,
                          int* __restrict__ ssrc) {
  int e = blockIdx.x * 256 + threadIdx.x;
  if (e < NE) {
    int dn = dst[e];
    int pos = rp[dn] + atomicAdd(&fill[dn], 1);
    ssrc[pos] = src[e];
  }
}

// feat = relu(h @ W^T + b); W row-major [64][64], out[n,d] = b[d] + sum_k h[n,k]*W[d,k]
__global__ void __launch_bounds__(256) k_fc_relu(const float* __restrict__ h,
                                                 const float* __restrict__ W,
                                                 const float* __restrict__ b,
                                                 float* __restrict__ out) {
  __shared__ float Wl[64 * 65];  // +1 pad -> bank (d+k)%32, 2-way = free
  __shared__ float bl[64];
  __shared__ float hl[16][64];
  int t = threadIdx.x;
  for (int i = t; i < 64 * 64; i += 256) Wl[(i >> 6) * 65 + (i & 63)] = W[i];
  if (t < 64) bl[t] = b[t];
  int base = blockIdx.x * 16;
  for (int i = t; i < 16 * 64; i += 256) {
    int r = i >> 6, c = i & 63;
    int node = base + r;
    hl[r][c] = (node < NN) ? h[node * DD + c] : 0.f;
  }
  __syncthreads();
  int d = t & 63, q = t >> 6;
  int n0 = q * 4;
  float a0 = bl[d], a1 = a0, a2 = a0, a3 = a0;
#pragma unroll
  for (int k = 0; k < 64; ++k) {
    float w = Wl[d * 65 + k];  // 2-way bank alias (free)
    a0 = fmaf(w, hl[n0 + 0][k], a0);  // broadcasts
    a1 = fmaf(w, hl[n0 + 1][k], a1);
    a2 = fmaf(w, hl[n0 + 2][k], a2);
    a3 = fmaf(w, hl[n0 + 3][k], a3);
  }
  int nd = base + n0;
  if (nd + 0 < NN) out[(nd + 0) * DD + d] = fmaxf(a0, 0.f);
  if (nd + 1 < NN) out[(nd + 1) * DD + d] = fmaxf(a1, 0.f);
  if (nd + 2 < NN) out[(nd + 2) * DD + d] = fmaxf(a2, 0.f);
  if (nd + 3 < NN) out[(nd + 3) * DD + d] = fmaxf(a3, 0.f);
}

// One wave per dst node: online softmax over incoming edges, fused message sum.
__global__ void __launch_bounds__(256) k_edge(const float* __restrict__ h,
                                              const float* __restrict__ feat,
                                              const int* __restrict__ rp,
                                              const int* __restrict__ ssrc,
                                              float* __restrict__ hout) {
  int d = threadIdx.x & 63;
  int node = blockIdx.x * 4 + (threadIdx.x >> 6);
  if (node >= NN) return;
  int beg = rp[node], end = rp[node + 1];
  float hd = h[node * DD + d];
  float m = -INFINITY, s = 0.f, acc = 0.f;
  for (int p = beg; p < end; ++p) {
    int si = ssrc[p] * DD;  // wave-uniform scalar load
    float e = h[si + d] * hd;
    float fs = feat[si + d];
    float nm = fmaxf(m, e);
    float sc = __expf(m - nm);
    float ex = __expf(e - nm);
    s = fmaf(s, sc, ex);
    acc = fmaf(acc, sc, fs * ex);
    m = nm;
  }
  hout[node * DD + d] = (end > beg) ? acc / s : 0.f;
}

__global__ void __launch_bounds__(256) k_final(const float* __restrict__ h0,
                                               const float* __restrict__ h1,
                                               const float* __restrict__ h2,
                                               float* __restrict__ out) {
  int d = threadIdx.x & 63;
  int node = blockIdx.x * 4 + (threadIdx.x >> 6);
  if (node >= NN) return;
  float v1 = h1[node * DD + d], v2 = h2[node * DD + d];
  float s1 = v1 * v1, s2 = v2 * v2;
#pragma unroll
  for (int off = 32; off > 0; off >>= 1) {
    s1 += __shfl_xor(s1, off, 64);
    s2 += __shfl_xor(s2, off, 64);
  }
  float r1 = v1 / fmaxf(sqrtf(s1), 1e-12f);
  float r2 = v2 / fmaxf(sqrtf(s2), 1e-12f);
  out[node * 192 + d] = h0[node * DD + d];
  out[node * 192 + 64 + d] = r1;
  out[node * 192 + 128 + d] = r2;
}

// -------------------- launch --------------------

extern "C" void kernel_launch(void* const* d_in, const int* in_sizes, int n_in,
                              void* d_out, int out_size, void* d_ws, size_t ws_size,
                              hipStream_t stream) {
  const int* node_ids = (const int*)d_in[0];
  const int* src = (const int*)d_in[1];
  const int* dst = (const int*)d_in[2];
  const float* emb = (const float*)d_in[3];
  const float* W0 = (const float*)d_in[4];
  const float* b0 = (const float*)d_in[5];
  const float* W1 = (const float*)d_in[8];
  const float* b1 = (const float*)d_in[9];
  float* out = (float*)d_out;

  size_t o = 0;
  auto alloc = [&](size_t nbytes) {
    char* p = (char*)d_ws + o;
    o += (nbytes + 255) & ~(size_t)255;
    return (void*)p;
  };
  float* h0 = (float*)alloc((size_t)NN * DD * 4);
  float* h1 = (float*)alloc((size_t)NN * DD * 4);
  float* h2 = (float*)alloc((size_t)NN * DD * 4);
  float* feat = (float*)alloc((size_t)NN * DD * 4);
  int* deg = (int*)alloc((size_t)2 * NN * 4);  // deg + fill contiguous
  int* fill = deg + NN;
  int* rp = (int*)alloc((size_t)(NN + 1) * 4);
  int* bsum = (int*)alloc(64 * 4);
  int* ssrc = (int*)alloc((size_t)NE * 4);
  (void)o; (void)ws_size; (void)in_sizes; (void)n_in; (void)out_size;

  hipMemsetAsync(deg, 0, (size_t)2 * NN * 4, stream);

  k_gather<<<(NN * DD + 255) / 256, 256, 0, stream>>>(emb, node_ids, h0);
  k_hist<<<(NE + 255) / 256, 256, 0, stream>>>(dst, deg);
  int NB = (NN + 1023) / 1024;
  k_scan1<<<NB, 1024, 0, stream>>>(deg, rp, bsum);
  k_scan2<<<1, 64, 0, stream>>>(bsum, NB);
  k_scan3<<<NB, 1024, 0, stream>>>(rp, bsum);
  k_scatter<<<(NE + 255) / 256, 256, 0, stream>>>(src, dst, rp, fill, ssrc);

  // layer 1
  k_fc_relu<<<(NN + 15) / 16, 256, 0, stream>>>(h0, W0, b0, feat);
  k_edge<<<(NN + 3) / 4, 256, 0, stream>>>(h0, feat, rp, ssrc, h1);
  // layer 2
  k_fc_relu<<<(NN + 15) / 16, 256, 0, stream>>>(h1, W1, b1, feat);
  k_edge<<<(NN + 3) / 4, 256, 0, stream>>>(h1, feat, rp, ssrc, h2);

  k_final<<<(NN + 3) / 4, 256, 0, stream>>>(h0, h1, h2, out);
}

// Round 2
// 337.371 us; speedup vs baseline: 1.1653x; 1.1653x over previous
//
#include <hip/hip_runtime.h>
#include <math.h>

#define NN 50000
#define NE 800000
#define DD 64

// -------------------- kernels --------------------

// gather h0 directly into out (stride 192) + histogram dst degrees
__global__ void k_prep(const float* __restrict__ emb, const int* __restrict__ ids,
                       const int* __restrict__ dst, float* __restrict__ out,
                       int* __restrict__ deg) {
  int idx = blockIdx.x * 256 + threadIdx.x;
  if (idx < NN * DD) {
    int node = idx >> 6, d = idx & 63;
    out[node * 192 + d] = emb[ids[node] * DD + d];
  }
  if (idx < NE) atomicAdd(&deg[dst[idx]], 1);
}

__global__ void k_scan1(const int* __restrict__ deg, int* __restrict__ rp,
                        int* __restrict__ bsum) {
  __shared__ int tmp[1024];
  int t = threadIdx.x;
  int i = blockIdx.x * 1024 + t;
  int v = (i < NN) ? deg[i] : 0;
  tmp[t] = v;
  __syncthreads();
  for (int off = 1; off < 1024; off <<= 1) {
    int x = (t >= off) ? tmp[t - off] : 0;
    __syncthreads();
    tmp[t] += x;
    __syncthreads();
  }
  if (i < NN) rp[i] = tmp[t] - v;  // exclusive within block
  if (t == 1023) bsum[blockIdx.x] = tmp[1023];
}

__global__ void k_scan2(int* __restrict__ bsum, int nb) {
  if (threadIdx.x == 0 && blockIdx.x == 0) {
    int r = 0;
    for (int i = 0; i < nb; ++i) { int v = bsum[i]; bsum[i] = r; r += v; }
  }
}

__global__ void k_scan3(int* __restrict__ rp, const int* __restrict__ bsum) {
  int i = blockIdx.x * 1024 + threadIdx.x;
  if (i < NN) rp[i] += bsum[blockIdx.x];
  if (i == 0) rp[NN] = NE;
}

__global__ void k_scatter(const int* __restrict__ src, const int* __restrict__ dst,
                          const int* __restrict__ rp, int* __restrict__ fill,
                          int* __restrict__ ssrc) {
  int e = blockIdx.x * 256 + threadIdx.x;
  if (e < NE) {
    int dn = dst[e];
    int pos = rp[dn] + atomicAdd(&fill[dn], 1);
    ssrc[pos] = src[e];
  }
}

// hf[n][d] = { h[n][d], relu(h @ W^T + b)[n][d] }  (interleaved float2)
__global__ void __launch_bounds__(256) k_fc_relu(const float* __restrict__ h, int hstride,
                                                 const float* __restrict__ W,
                                                 const float* __restrict__ b,
                                                 float2* __restrict__ hf) {
  __shared__ float Wl[64 * 65];  // +1 pad -> 2-way bank alias (free)
  __shared__ float bl[64];
  __shared__ float hl[16][64];
  int t = threadIdx.x;
  for (int i = t; i < 64 * 64; i += 256) Wl[(i >> 6) * 65 + (i & 63)] = W[i];
  if (t < 64) bl[t] = b[t];
  int base = blockIdx.x * 16;
  for (int i = t; i < 16 * 64; i += 256) {
    int r = i >> 6, c = i & 63;
    int node = base + r;
    hl[r][c] = (node < NN) ? h[node * hstride + c] : 0.f;
  }
  __syncthreads();
  int d = t & 63, q = t >> 6;
  int n0 = q * 4;
  float a0 = bl[d], a1 = a0, a2 = a0, a3 = a0;
#pragma unroll
  for (int k = 0; k < 64; ++k) {
    float w = Wl[d * 65 + k];
    a0 = fmaf(w, hl[n0 + 0][k], a0);
    a1 = fmaf(w, hl[n0 + 1][k], a1);
    a2 = fmaf(w, hl[n0 + 2][k], a2);
    a3 = fmaf(w, hl[n0 + 3][k], a3);
  }
  int nd = base + n0;
  if (nd + 0 < NN) hf[(nd + 0) * DD + d] = make_float2(hl[n0 + 0][d], fmaxf(a0, 0.f));
  if (nd + 1 < NN) hf[(nd + 1) * DD + d] = make_float2(hl[n0 + 1][d], fmaxf(a1, 0.f));
  if (nd + 2 < NN) hf[(nd + 2) * DD + d] = make_float2(hl[n0 + 2][d], fmaxf(a2, 0.f));
  if (nd + 3 < NN) hf[(nd + 3) * DD + d] = make_float2(hl[n0 + 3][d], fmaxf(a3, 0.f));
}

// One wave per dst node. |e| = |h_src*h_dst| is bounded (<~1) so softmax needs
// no max-subtraction -> 4 independent (s,acc) partials, unroll-4 load pipeline.
__global__ void __launch_bounds__(256) k_edge(const float2* __restrict__ hf,
                                              const int* __restrict__ rp,
                                              const int* __restrict__ ssrc,
                                              float* __restrict__ hout, int ostride) {
  int d = threadIdx.x & 63;
  int node = blockIdx.x * 4 + (threadIdx.x >> 6);
  if (node >= NN) return;
  int beg = rp[node], end = rp[node + 1];
  float hd = hf[node * DD + d].x;
  float s0 = 0.f, s1 = 0.f, s2 = 0.f, s3 = 0.f;
  float a0 = 0.f, a1 = 0.f, a2 = 0.f, a3 = 0.f;
  int p = beg;
  for (; p + 4 <= end; p += 4) {
    int i0 = ssrc[p] * DD, i1 = ssrc[p + 1] * DD;
    int i2 = ssrc[p + 2] * DD, i3 = ssrc[p + 3] * DD;
    float2 v0 = hf[i0 + d], v1 = hf[i1 + d], v2 = hf[i2 + d], v3 = hf[i3 + d];
    float e0 = __expf(v0.x * hd); s0 += e0; a0 = fmaf(v0.y, e0, a0);
    float e1 = __expf(v1.x * hd); s1 += e1; a1 = fmaf(v1.y, e1, a1);
    float e2 = __expf(v2.x * hd); s2 += e2; a2 = fmaf(v2.y, e2, a2);
    float e3 = __expf(v3.x * hd); s3 += e3; a3 = fmaf(v3.y, e3, a3);
  }
  for (; p < end; ++p) {
    int i0 = ssrc[p] * DD;
    float2 v0 = hf[i0 + d];
    float e0 = __expf(v0.x * hd); s0 += e0; a0 = fmaf(v0.y, e0, a0);
  }
  float s = (s0 + s1) + (s2 + s3);
  float a = (a0 + a1) + (a2 + a3);
  hout[node * ostride + d] = (end > beg) ? a / s : 0.f;
}

// normalize h1 -> out[64..127]; normalize out[128..191] (h2, unnormalized) in place
__global__ void __launch_bounds__(256) k_final(const float* __restrict__ h1,
                                               float* __restrict__ out) {
  int d = threadIdx.x & 63;
  int node = blockIdx.x * 4 + (threadIdx.x >> 6);
  if (node >= NN) return;
  float v1 = h1[node * DD + d], v2 = out[node * 192 + 128 + d];
  float s1 = v1 * v1, s2 = v2 * v2;
#pragma unroll
  for (int off = 32; off > 0; off >>= 1) {
    s1 += __shfl_xor(s1, off, 64);
    s2 += __shfl_xor(s2, off, 64);
  }
  float r1 = v1 / fmaxf(sqrtf(s1), 1e-12f);
  float r2 = v2 / fmaxf(sqrtf(s2), 1e-12f);
  out[node * 192 + 64 + d] = r1;
  out[node * 192 + 128 + d] = r2;
}

// -------------------- launch --------------------

extern "C" void kernel_launch(void* const* d_in, const int* in_sizes, int n_in,
                              void* d_out, int out_size, void* d_ws, size_t ws_size,
                              hipStream_t stream) {
  const int* node_ids = (const int*)d_in[0];
  const int* src = (const int*)d_in[1];
  const int* dst = (const int*)d_in[2];
  const float* emb = (const float*)d_in[3];
  const float* W0 = (const float*)d_in[4];
  const float* b0 = (const float*)d_in[5];
  const float* W1 = (const float*)d_in[8];
  const float* b1 = (const float*)d_in[9];
  float* out = (float*)d_out;

  size_t o = 0;
  auto alloc = [&](size_t nbytes) {
    char* p = (char*)d_ws + o;
    o += (nbytes + 255) & ~(size_t)255;
    return (void*)p;
  };
  float* h1 = (float*)alloc((size_t)NN * DD * 4);
  float2* hf = (float2*)alloc((size_t)NN * DD * 8);
  int* deg = (int*)alloc((size_t)2 * NN * 4);  // deg + fill contiguous
  int* fill = deg + NN;
  int* rp = (int*)alloc((size_t)(NN + 1) * 4);
  int* bsum = (int*)alloc(64 * 4);
  int* ssrc = (int*)alloc((size_t)NE * 4);
  (void)o; (void)ws_size; (void)in_sizes; (void)n_in; (void)out_size;

  hipMemsetAsync(deg, 0, (size_t)2 * NN * 4, stream);

  k_prep<<<(NN * DD + 255) / 256, 256, 0, stream>>>(emb, node_ids, dst, out, deg);
  int NB = (NN + 1023) / 1024;
  k_scan1<<<NB, 1024, 0, stream>>>(deg, rp, bsum);
  k_scan2<<<1, 64, 0, stream>>>(bsum, NB);
  k_scan3<<<NB, 1024, 0, stream>>>(rp, bsum);
  k_scatter<<<(NE + 255) / 256, 256, 0, stream>>>(src, dst, rp, fill, ssrc);

  // layer 1: h0 lives in out (stride 192); h1 -> scratch (stride 64)
  k_fc_relu<<<(NN + 15) / 16, 256, 0, stream>>>(out, 192, W0, b0, hf);
  k_edge<<<(NN + 3) / 4, 256, 0, stream>>>(hf, rp, ssrc, h1, DD);
  // layer 2: h1 (stride 64) -> h2 directly into out cols 128..191 (stride 192)
  k_fc_relu<<<(NN + 15) / 16, 256, 0, stream>>>(h1, DD, W1, b1, hf);
  k_edge<<<(NN + 3) / 4, 256, 0, stream>>>(hf, rp, ssrc, out + 128, 192);

  k_final<<<(NN + 3) / 4, 256, 0, stream>>>(h1, out);
}

// Round 3
// 259.612 us; speedup vs baseline: 1.5144x; 1.2995x over previous
//
#include <hip/hip_runtime.h>
#include <math.h>

#define NN 50000
#define NE 800000
#define DD 64

__device__ __forceinline__ unsigned bf16r(float x) {  // round-to-nearest-even bf16
  unsigned u = __float_as_uint(x);
  return (u + 0x7fffu + ((u >> 16) & 1u)) >> 16;
}

// -------------------- kernels --------------------

// gather h0 into out (stride 192) + histogram dst degrees, capturing position
__global__ void k_prep(const float* __restrict__ emb, const int* __restrict__ ids,
                       const int* __restrict__ dst, float* __restrict__ out,
                       int* __restrict__ deg, int* __restrict__ pos) {
  int idx = blockIdx.x * 256 + threadIdx.x;
  if (idx < NN * DD) {
    int node = idx >> 6, d = idx & 63;
    out[node * 192 + d] = emb[ids[node] * DD + d];
  }
  if (idx < NE) pos[idx] = atomicAdd(&deg[dst[idx]], 1);
}

__global__ void k_scan1(const int* __restrict__ deg, int* __restrict__ rp,
                        int* __restrict__ bsum) {
  __shared__ int tmp[1024];
  int t = threadIdx.x;
  int i = blockIdx.x * 1024 + t;
  int v = (i < NN) ? deg[i] : 0;
  tmp[t] = v;
  __syncthreads();
  for (int off = 1; off < 1024; off <<= 1) {
    int x = (t >= off) ? tmp[t - off] : 0;
    __syncthreads();
    tmp[t] += x;
    __syncthreads();
  }
  if (i < NN) rp[i] = tmp[t] - v;  // exclusive within block
  if (t == 1023) bsum[blockIdx.x] = tmp[1023];
}

// exclusive scan of <=64 block sums with one wave
__global__ void k_scan2(int* __restrict__ bsum, int nb) {
  int t = threadIdx.x;
  int orig = (t < nb) ? bsum[t] : 0;
  int v = orig;
#pragma unroll
  for (int off = 1; off < 64; off <<= 1) {
    int x = __shfl_up(v, off, 64);
    if (t >= off) v += x;
  }
  if (t < nb) bsum[t] = v - orig;
}

__global__ void k_scan3(int* __restrict__ rp, const int* __restrict__ bsum) {
  int i = blockIdx.x * 1024 + threadIdx.x;
  if (i < NN) rp[i] += bsum[blockIdx.x];
  if (i == 0) rp[NN] = NE;
}

// atomic-free scatter using captured positions
__global__ void k_scatter(const int* __restrict__ src, const int* __restrict__ dst,
                          const int* __restrict__ rp, const int* __restrict__ pos,
                          int* __restrict__ ssrc) {
  int e = blockIdx.x * 256 + threadIdx.x;
  if (e < NE) ssrc[rp[dst[e]] + pos[e]] = src[e];
}

// hfb[n*64+d] = pack(bf16(h[n][d]), bf16(relu(h @ W^T + b)[n][d]))
__global__ void __launch_bounds__(256) k_fc_relu(const float* __restrict__ h, int hstride,
                                                 const float* __restrict__ W,
                                                 const float* __restrict__ b,
                                                 unsigned* __restrict__ hfb) {
  __shared__ float Wl[64 * 65];  // +1 pad -> 2-way bank alias (free)
  __shared__ float bl[64];
  __shared__ float hl[16][64];
  int t = threadIdx.x;
  for (int i = t; i < 64 * 64; i += 256) Wl[(i >> 6) * 65 + (i & 63)] = W[i];
  if (t < 64) bl[t] = b[t];
  int base = blockIdx.x * 16;
  for (int i = t; i < 16 * 64; i += 256) {
    int r = i >> 6, c = i & 63;
    int node = base + r;
    hl[r][c] = (node < NN) ? h[node * hstride + c] : 0.f;
  }
  __syncthreads();
  int d = t & 63, q = t >> 6;
  int n0 = q * 4;
  float a0 = bl[d], a1 = a0, a2 = a0, a3 = a0;
#pragma unroll
  for (int k = 0; k < 64; ++k) {
    float w = Wl[d * 65 + k];
    a0 = fmaf(w, hl[n0 + 0][k], a0);
    a1 = fmaf(w, hl[n0 + 1][k], a1);
    a2 = fmaf(w, hl[n0 + 2][k], a2);
    a3 = fmaf(w, hl[n0 + 3][k], a3);
  }
  int nd = base + n0;
  if (nd + 0 < NN) hfb[(nd + 0) * DD + d] = bf16r(hl[n0 + 0][d]) | (bf16r(fmaxf(a0, 0.f)) << 16);
  if (nd + 1 < NN) hfb[(nd + 1) * DD + d] = bf16r(hl[n0 + 1][d]) | (bf16r(fmaxf(a1, 0.f)) << 16);
  if (nd + 2 < NN) hfb[(nd + 2) * DD + d] = bf16r(hl[n0 + 2][d]) | (bf16r(fmaxf(a2, 0.f)) << 16);
  if (nd + 3 < NN) hfb[(nd + 3) * DD + d] = bf16r(hl[n0 + 3][d]) | (bf16r(fmaxf(a3, 0.f)) << 16);
}

// One wave per dst node. |e| bounded -> softmax without max-subtraction.
// bf16-packed gather: one u32 per lane per edge. 8 independent partials.
__global__ void __launch_bounds__(256) k_edge(const unsigned* __restrict__ hfb,
                                              const float* __restrict__ hsrc, int hstride,
                                              const int* __restrict__ rp,
                                              const int* __restrict__ ssrc,
                                              float* __restrict__ hout, int ostride) {
  int d = threadIdx.x & 63;
  int node = blockIdx.x * 4 + (threadIdx.x >> 6);
  if (node >= NN) return;
  int beg = rp[node], end = rp[node + 1];
  float hd = hsrc[node * hstride + d];
  float s0 = 0.f, s1 = 0.f, s2 = 0.f, s3 = 0.f;
  float s4 = 0.f, s5 = 0.f, s6 = 0.f, s7 = 0.f;
  float a0 = 0.f, a1 = 0.f, a2 = 0.f, a3 = 0.f;
  float a4 = 0.f, a5 = 0.f, a6 = 0.f, a7 = 0.f;
  int p = beg;
#define EDGE_STEP(j, sj, aj)                                        \
  {                                                                 \
    unsigned v = hfb[ssrc[p + j] * DD + d];                         \
    float hv = __uint_as_float(v << 16);                            \
    float fv = __uint_as_float(v & 0xffff0000u);                    \
    float ex = __expf(hv * hd);                                     \
    sj += ex;                                                       \
    aj = fmaf(fv, ex, aj);                                          \
  }
  for (; p + 8 <= end; p += 8) {
    EDGE_STEP(0, s0, a0) EDGE_STEP(1, s1, a1) EDGE_STEP(2, s2, a2) EDGE_STEP(3, s3, a3)
    EDGE_STEP(4, s4, a4) EDGE_STEP(5, s5, a5) EDGE_STEP(6, s6, a6) EDGE_STEP(7, s7, a7)
  }
  for (; p < end; ++p) EDGE_STEP(0, s0, a0)
#undef EDGE_STEP
  float s = ((s0 + s1) + (s2 + s3)) + ((s4 + s5) + (s6 + s7));
  float a = ((a0 + a1) + (a2 + a3)) + ((a4 + a5) + (a6 + a7));
  hout[node * ostride + d] = (end > beg) ? a / s : 0.f;
}

// normalize h1 -> out[64..127]; normalize out[128..191] (h2) in place
__global__ void __launch_bounds__(256) k_final(const float* __restrict__ h1,
                                               float* __restrict__ out) {
  int d = threadIdx.x & 63;
  int node = blockIdx.x * 4 + (threadIdx.x >> 6);
  if (node >= NN) return;
  float v1 = h1[node * DD + d], v2 = out[node * 192 + 128 + d];
  float s1 = v1 * v1, s2 = v2 * v2;
#pragma unroll
  for (int off = 32; off > 0; off >>= 1) {
    s1 += __shfl_xor(s1, off, 64);
    s2 += __shfl_xor(s2, off, 64);
  }
  out[node * 192 + 64 + d] = v1 / fmaxf(sqrtf(s1), 1e-12f);
  out[node * 192 + 128 + d] = v2 / fmaxf(sqrtf(s2), 1e-12f);
}

// -------------------- launch --------------------

extern "C" void kernel_launch(void* const* d_in, const int* in_sizes, int n_in,
                              void* d_out, int out_size, void* d_ws, size_t ws_size,
                              hipStream_t stream) {
  const int* node_ids = (const int*)d_in[0];
  const int* src = (const int*)d_in[1];
  const int* dst = (const int*)d_in[2];
  const float* emb = (const float*)d_in[3];
  const float* W0 = (const float*)d_in[4];
  const float* b0 = (const float*)d_in[5];
  const float* W1 = (const float*)d_in[8];
  const float* b1 = (const float*)d_in[9];
  float* out = (float*)d_out;

  size_t o = 0;
  auto alloc = [&](size_t nbytes) {
    char* p = (char*)d_ws + o;
    o += (nbytes + 255) & ~(size_t)255;
    return (void*)p;
  };
  float* h1 = (float*)alloc((size_t)NN * DD * 4);
  unsigned* hfb = (unsigned*)alloc((size_t)NN * DD * 4);
  int* deg = (int*)alloc((size_t)NN * 4);
  int* rp = (int*)alloc((size_t)(NN + 1) * 4);
  int* bsum = (int*)alloc(64 * 4);
  int* ssrc = (int*)alloc((size_t)NE * 4);
  int* pos = (int*)alloc((size_t)NE * 4);
  (void)o; (void)ws_size; (void)in_sizes; (void)n_in; (void)out_size;

  hipMemsetAsync(deg, 0, (size_t)NN * 4, stream);

  k_prep<<<(NN * DD + 255) / 256, 256, 0, stream>>>(emb, node_ids, dst, out, deg, pos);
  int NB = (NN + 1023) / 1024;
  k_scan1<<<NB, 1024, 0, stream>>>(deg, rp, bsum);
  k_scan2<<<1, 64, 0, stream>>>(bsum, NB);
  k_scan3<<<NB, 1024, 0, stream>>>(rp, bsum);
  k_scatter<<<(NE + 255) / 256, 256, 0, stream>>>(src, dst, rp, pos, ssrc);

  // layer 1: h0 lives in out (stride 192); h1 -> scratch (stride 64)
  k_fc_relu<<<(NN + 15) / 16, 256, 0, stream>>>(out, 192, W0, b0, hfb);
  k_edge<<<(NN + 3) / 4, 256, 0, stream>>>(hfb, out, 192, rp, ssrc, h1, DD);
  // layer 2
  k_fc_relu<<<(NN + 15) / 16, 256, 0, stream>>>(h1, DD, W1, b1, hfb);
  k_edge<<<(NN + 3) / 4, 256, 0, stream>>>(hfb, h1, DD, rp, ssrc, out + 128, 192);

  k_final<<<(NN + 3) / 4, 256, 0, stream>>>(h1, out);
}

// Round 4
// 186.382 us; speedup vs baseline: 2.1094x; 1.3929x over previous
//
#include <hip/hip_runtime.h>
#include <math.h>

#define NN 50000
#define NE 800000
#define DD 64

typedef __attribute__((ext_vector_type(8))) short short8v;
typedef __attribute__((ext_vector_type(4))) float floatx4;

__device__ __forceinline__ unsigned bf16r(float x) {  // round-to-nearest-even bf16
  unsigned u = __float_as_uint(x);
  return (u + 0x7fffu + ((u >> 16) & 1u)) >> 16;
}

// -------------------- kernels --------------------

// gather h0 into out (stride 192) + histogram dst degrees, capturing position
__global__ void k_prep(const float* __restrict__ emb, const int* __restrict__ ids,
                       const int* __restrict__ dst, float* __restrict__ out,
                       int* __restrict__ deg, int* __restrict__ pos) {
  int idx = blockIdx.x * 256 + threadIdx.x;
  if (idx < NN * DD) {
    int node = idx >> 6, d = idx & 63;
    out[node * 192 + d] = emb[ids[node] * DD + d];
  }
  if (idx < NE) pos[idx] = atomicAdd(&deg[dst[idx]], 1);
}

__global__ void k_scan1(const int* __restrict__ deg, int* __restrict__ rp,
                        int* __restrict__ bsum) {
  __shared__ int tmp[1024];
  int t = threadIdx.x;
  int i = blockIdx.x * 1024 + t;
  int v = (i < NN) ? deg[i] : 0;
  tmp[t] = v;
  __syncthreads();
  for (int off = 1; off < 1024; off <<= 1) {
    int x = (t >= off) ? tmp[t - off] : 0;
    __syncthreads();
    tmp[t] += x;
    __syncthreads();
  }
  if (i < NN) rp[i] = tmp[t] - v;  // exclusive within block
  if (t == 1023) bsum[blockIdx.x] = tmp[1023];
}

// exclusive scan of <=64 block sums with one wave
__global__ void k_scan2(int* __restrict__ bsum, int nb) {
  int t = threadIdx.x;
  int orig = (t < nb) ? bsum[t] : 0;
  int v = orig;
#pragma unroll
  for (int off = 1; off < 64; off <<= 1) {
    int x = __shfl_up(v, off, 64);
    if (t >= off) v += x;
  }
  if (t < nb) bsum[t] = v - orig;
}

__global__ void k_scan3(int* __restrict__ rp, const int* __restrict__ bsum) {
  int i = blockIdx.x * 1024 + threadIdx.x;
  if (i < NN) rp[i] += bsum[blockIdx.x];
  if (i == 0) rp[NN] = NE;
}

// atomic-free scatter using captured positions
__global__ void k_scatter(const int* __restrict__ src, const int* __restrict__ dst,
                          const int* __restrict__ rp, const int* __restrict__ pos,
                          int* __restrict__ ssrc) {
  int e = blockIdx.x * 256 + threadIdx.x;
  if (e < NE) ssrc[rp[dst[e]] + pos[e]] = src[e];
}

// MFMA FC: hfb[n*64+d] = pack(bf16(h[n][d]), bf16(relu(h @ W^T + b)[n][d]))
// One wave per 16-node strip, no LDS. A = h[16x64] bf16, B = W^T (B[k][d]=W[d][k]).
// 16x16x32 frag layout: A row = lane&15, k = (lane>>4)*8 + i  (8 consecutive)
//                       B col = lane&15, k = (lane>>4)*8 + i
//                       D col = lane&15, row = (lane>>4)*4 + reg
__global__ void __launch_bounds__(256) k_fc_mfma(const float* __restrict__ h, int hstride,
                                                 const float* __restrict__ W,
                                                 const float* __restrict__ b,
                                                 unsigned* __restrict__ hfb) {
  int lane = threadIdx.x & 63;
  int wid = threadIdx.x >> 6;
  int nbase = blockIdx.x * 64 + wid * 16;
  if (nbase >= NN) return;  // strips are exactly aligned: 50000 = 3125*16
  int r16 = lane & 15, kg = lane >> 4;

  // A fragments (2 k-tiles)
  short8v afr[2];
  const float* hrow = h + (size_t)(nbase + r16) * hstride;
#pragma unroll
  for (int kt = 0; kt < 2; ++kt) {
    int k0 = kt * 32 + kg * 8;
#pragma unroll
    for (int i = 0; i < 8; ++i) afr[kt][i] = (short)bf16r(hrow[k0 + i]);
  }
  // B fragments (4 d-tiles x 2 k-tiles), W is identical for all waves -> L2-hot
  short8v bfr[4][2];
#pragma unroll
  for (int dt = 0; dt < 4; ++dt) {
    const float* wrow = W + (dt * 16 + r16) * 64;
#pragma unroll
    for (int kt = 0; kt < 2; ++kt) {
      int k0 = kt * 32 + kg * 8;
#pragma unroll
      for (int i = 0; i < 8; ++i) bfr[dt][kt][i] = (short)bf16r(wrow[k0 + i]);
    }
  }
#pragma unroll
  for (int dt = 0; dt < 4; ++dt) {
    floatx4 acc = {0.f, 0.f, 0.f, 0.f};
    acc = __builtin_amdgcn_mfma_f32_16x16x32_bf16(afr[0], bfr[dt][0], acc, 0, 0, 0);
    acc = __builtin_amdgcn_mfma_f32_16x16x32_bf16(afr[1], bfr[dt][1], acc, 0, 0, 0);
    int d = dt * 16 + r16;
    float bias = b[d];
#pragma unroll
    for (int r = 0; r < 4; ++r) {
      int node = nbase + kg * 4 + r;
      float feat = fmaxf(acc[r] + bias, 0.f);
      float hv = h[(size_t)node * hstride + d];
      hfb[node * DD + d] = bf16r(hv) | (bf16r(feat) << 16);
    }
  }
}

// One wave per dst node. |e| bounded -> softmax without max-subtraction.
// bf16-packed gather: one u32 per lane per edge. 8 independent partials.
__global__ void __launch_bounds__(256) k_edge(const unsigned* __restrict__ hfb,
                                              const float* __restrict__ hsrc, int hstride,
                                              const int* __restrict__ rp,
                                              const int* __restrict__ ssrc,
                                              float* __restrict__ hout, int ostride) {
  int d = threadIdx.x & 63;
  int node = blockIdx.x * 4 + (threadIdx.x >> 6);
  if (node >= NN) return;
  int beg = rp[node], end = rp[node + 1];
  float hd = hsrc[node * hstride + d];
  float s0 = 0.f, s1 = 0.f, s2 = 0.f, s3 = 0.f;
  float s4 = 0.f, s5 = 0.f, s6 = 0.f, s7 = 0.f;
  float a0 = 0.f, a1 = 0.f, a2 = 0.f, a3 = 0.f;
  float a4 = 0.f, a5 = 0.f, a6 = 0.f, a7 = 0.f;
  int p = beg;
#define EDGE_STEP(j, sj, aj)                                        \
  {                                                                 \
    unsigned v = hfb[ssrc[p + j] * DD + d];                         \
    float hv = __uint_as_float(v << 16);                            \
    float fv = __uint_as_float(v & 0xffff0000u);                    \
    float ex = __expf(hv * hd);                                     \
    sj += ex;                                                       \
    aj = fmaf(fv, ex, aj);                                          \
  }
  for (; p + 8 <= end; p += 8) {
    EDGE_STEP(0, s0, a0) EDGE_STEP(1, s1, a1) EDGE_STEP(2, s2, a2) EDGE_STEP(3, s3, a3)
    EDGE_STEP(4, s4, a4) EDGE_STEP(5, s5, a5) EDGE_STEP(6, s6, a6) EDGE_STEP(7, s7, a7)
  }
  for (; p < end; ++p) EDGE_STEP(0, s0, a0)
#undef EDGE_STEP
  float s = ((s0 + s1) + (s2 + s3)) + ((s4 + s5) + (s6 + s7));
  float a = ((a0 + a1) + (a2 + a3)) + ((a4 + a5) + (a6 + a7));
  hout[node * ostride + d] = (end > beg) ? a / s : 0.f;
}

// normalize h1 -> out[64..127]; normalize out[128..191] (h2) in place
__global__ void __launch_bounds__(256) k_final(const float* __restrict__ h1,
                                               float* __restrict__ out) {
  int d = threadIdx.x & 63;
  int node = blockIdx.x * 4 + (threadIdx.x >> 6);
  if (node >= NN) return;
  float v1 = h1[node * DD + d], v2 = out[node * 192 + 128 + d];
  float s1 = v1 * v1, s2 = v2 * v2;
#pragma unroll
  for (int off = 32; off > 0; off >>= 1) {
    s1 += __shfl_xor(s1, off, 64);
    s2 += __shfl_xor(s2, off, 64);
  }
  out[node * 192 + 64 + d] = v1 / fmaxf(sqrtf(s1), 1e-12f);
  out[node * 192 + 128 + d] = v2 / fmaxf(sqrtf(s2), 1e-12f);
}

// -------------------- launch --------------------

extern "C" void kernel_launch(void* const* d_in, const int* in_sizes, int n_in,
                              void* d_out, int out_size, void* d_ws, size_t ws_size,
                              hipStream_t stream) {
  const int* node_ids = (const int*)d_in[0];
  const int* src = (const int*)d_in[1];
  const int* dst = (const int*)d_in[2];
  const float* emb = (const float*)d_in[3];
  const float* W0 = (const float*)d_in[4];
  const float* b0 = (const float*)d_in[5];
  const float* W1 = (const float*)d_in[8];
  const float* b1 = (const float*)d_in[9];
  float* out = (float*)d_out;

  size_t o = 0;
  auto alloc = [&](size_t nbytes) {
    char* p = (char*)d_ws + o;
    o += (nbytes + 255) & ~(size_t)255;
    return (void*)p;
  };
  float* h1 = (float*)alloc((size_t)NN * DD * 4);
  unsigned* hfb = (unsigned*)alloc((size_t)NN * DD * 4);
  int* deg = (int*)alloc((size_t)NN * 4);
  int* rp = (int*)alloc((size_t)(NN + 1) * 4);
  int* bsum = (int*)alloc(64 * 4);
  int* ssrc = (int*)alloc((size_t)NE * 4);
  int* pos = (int*)alloc((size_t)NE * 4);
  (void)o; (void)ws_size; (void)in_sizes; (void)n_in; (void)out_size;

  hipMemsetAsync(deg, 0, (size_t)NN * 4, stream);

  k_prep<<<(NN * DD + 255) / 256, 256, 0, stream>>>(emb, node_ids, dst, out, deg, pos);
  int NB = (NN + 1023) / 1024;
  k_scan1<<<NB, 1024, 0, stream>>>(deg, rp, bsum);
  k_scan2<<<1, 64, 0, stream>>>(bsum, NB);
  k_scan3<<<NB, 1024, 0, stream>>>(rp, bsum);
  k_scatter<<<(NE + 255) / 256, 256, 0, stream>>>(src, dst, rp, pos, ssrc);

  // layer 1: h0 lives in out (stride 192); h1 -> scratch (stride 64)
  k_fc_mfma<<<(NN + 63) / 64, 256, 0, stream>>>(out, 192, W0, b0, hfb);
  k_edge<<<(NN + 3) / 4, 256, 0, stream>>>(hfb, out, 192, rp, ssrc, h1, DD);
  // layer 2
  k_fc_mfma<<<(NN + 63) / 64, 256, 0, stream>>>(h1, DD, W1, b1, hfb);
  k_edge<<<(NN + 3) / 4, 256, 0, stream>>>(hfb, h1, DD, rp, ssrc, out + 128, 192);

  k_final<<<(NN + 3) / 4, 256, 0, stream>>>(h1, out);
}